// Round 1
// baseline (900.222 us; speedup 1.0000x reference)
//
#include <hip/hip_runtime.h>
#include <float.h>
#include <math.h>

// Problem geometry
#define ZM 8192       // spatial rows = 8*32*32
#define CN 16384      // codebook entries
#define KD 256        // embedding dim
#define HWN 1024      // 32*32
#define ZSTRIDE 262144 // 256*1024 (per-batch stride in z)

// GEMM tiling
#define BM 128
#define BN 128
#define KT 32
#define NC 16         // N chunks (grid.y)
#define BNP 132       // padded LDS row for B (bank-conflict mitigation + 16B align)

// ---------------- norms ----------------

__global__ void norm_z_kernel(const float* __restrict__ z, float* __restrict__ zrinv) {
    __shared__ float sm[4];
    int row = blockIdx.x;              // 0..8191
    int b = row >> 10, hw = row & (HWN - 1);
    int c = threadIdx.x;               // 0..255
    float v = z[(size_t)b * ZSTRIDE + (size_t)c * HWN + hw];
    float s = v * v;
    #pragma unroll
    for (int m = 32; m; m >>= 1) s += __shfl_xor(s, m, 64);
    if ((threadIdx.x & 63) == 0) sm[threadIdx.x >> 6] = s;
    __syncthreads();
    if (threadIdx.x == 0) {
        float t = sm[0] + sm[1] + sm[2] + sm[3];
        zrinv[row] = 1.0f / fmaxf(sqrtf(t), 1e-12f);
    }
}

__global__ void norm_cb_kernel(const float* __restrict__ cb,
                               float* __restrict__ cbrinv, float* __restrict__ cbsq) {
    __shared__ float sm[4];
    int n = blockIdx.x;                // 0..16383
    float v = cb[(size_t)n * KD + threadIdx.x];
    float s = v * v;
    #pragma unroll
    for (int m = 32; m; m >>= 1) s += __shfl_xor(s, m, 64);
    if ((threadIdx.x & 63) == 0) sm[threadIdx.x >> 6] = s;
    __syncthreads();
    if (threadIdx.x == 0) {
        float t = sm[0] + sm[1] + sm[2] + sm[3];
        float r = 1.0f / fmaxf(sqrtf(t), 1e-12f);
        cbrinv[n] = r;
        cbsq[n] = t * r * r;           // ||normalized cb||^2 (~1, kept for fidelity)
    }
}

// ---------------- fused GEMM + argmin ----------------
// score(row, n) = zrinv[row]*dot(z_row, cb_n*cbrinv[n]) - 0.5*cbsq[n]
// argmax(score) == argmin(reference distance). First (lowest) index wins ties.

__global__ __launch_bounds__(256) void gemm_argmin_kernel(
    const float* __restrict__ z, const float* __restrict__ cb,
    const float* __restrict__ zrinv, const float* __restrict__ cbrinv,
    const float* __restrict__ cbsq,
    float* __restrict__ bval, int* __restrict__ bidx)
{
    __shared__ float As[KT][BM];   // k-major, rows contiguous
    __shared__ float Bs[KT][BNP];  // k-major, cols contiguous (transposed on load)

    const int tid = threadIdx.x;
    const int tx = tid & 15, ty = tid >> 4;
    const int row0 = blockIdx.x * BM;          // row block (z is contiguous in hw here)
    const int chunk = blockIdx.y;              // N chunk

    // z[b][k][hw]: for this row block, rows are 128 contiguous floats at fixed k
    const float* zbase = z + (size_t)(row0 >> 10) * ZSTRIDE + (row0 & (HWN - 1));

    // loader coordinates
    const int a_r4 = (tid & 31) * 4;   // row offset (float4)
    const int a_k  = tid >> 5;         // 0..7
    const int b_c  = tid >> 3;         // 0..31
    const int b_k4 = (tid & 7) * 4;    // k offset (float4)

    float zr[8];
    #pragma unroll
    for (int i = 0; i < 8; ++i) zr[i] = zrinv[row0 + ty * 8 + i];

    float best[8]; int bi_[8];
    #pragma unroll
    for (int i = 0; i < 8; ++i) { best[i] = -FLT_MAX; bi_[i] = 0; }

    const int tiles = (CN / NC) / BN;  // 8

    for (int t = 0; t < tiles; ++t) {
        const int col0 = chunk * (CN / NC) + t * BN;

        float acc[8][8];
        #pragma unroll
        for (int i = 0; i < 8; ++i)
            #pragma unroll
            for (int j = 0; j < 8; ++j) acc[i][j] = 0.0f;

        for (int k0 = 0; k0 < KD; k0 += KT) {
            // stage A: 32k x 128r, pure contiguous copies
            #pragma unroll
            for (int u = 0; u < 4; ++u) {
                int k = a_k + u * 8;
                float4 v = *(const float4*)(zbase + (size_t)(k0 + k) * HWN + a_r4);
                *(float4*)&As[k][a_r4] = v;
            }
            // stage B: transpose cb[n][k] -> Bs[k][c], scaled by cbrinv[n]
            #pragma unroll
            for (int u = 0; u < 4; ++u) {
                int c = b_c + u * 32;
                int n = col0 + c;
                float4 v = *(const float4*)(cb + (size_t)n * KD + k0 + b_k4);
                float sc = cbrinv[n];
                Bs[b_k4 + 0][c] = v.x * sc;
                Bs[b_k4 + 1][c] = v.y * sc;
                Bs[b_k4 + 2][c] = v.z * sc;
                Bs[b_k4 + 3][c] = v.w * sc;
            }
            __syncthreads();

            #pragma unroll
            for (int kk = 0; kk < KT; ++kk) {
                float4 a0 = *(const float4*)&As[kk][ty * 8];
                float4 a1 = *(const float4*)&As[kk][ty * 8 + 4];
                float4 b0 = *(const float4*)&Bs[kk][tx * 8];
                float4 b1 = *(const float4*)&Bs[kk][tx * 8 + 4];
                float a[8] = {a0.x, a0.y, a0.z, a0.w, a1.x, a1.y, a1.z, a1.w};
                float b[8] = {b0.x, b0.y, b0.z, b0.w, b1.x, b1.y, b1.z, b1.w};
                #pragma unroll
                for (int i = 0; i < 8; ++i)
                    #pragma unroll
                    for (int j = 0; j < 8; ++j)
                        acc[i][j] = fmaf(a[i], b[j], acc[i][j]);
            }
            __syncthreads();
        }

        // epilogue: per-row argmax over this 128-col tile
        float cq[8];
        #pragma unroll
        for (int j = 0; j < 8; ++j) cq[j] = cbsq[col0 + tx * 8 + j];

        #pragma unroll
        for (int i = 0; i < 8; ++i) {
            float bv = -FLT_MAX; int bj = 0;
            #pragma unroll
            for (int j = 0; j < 8; ++j) {
                float s = fmaf(zr[i], acc[i][j], -0.5f * cq[j]);
                if (s > bv) { bv = s; bj = col0 + tx * 8 + j; }  // strict > keeps lowest idx
            }
            // butterfly across the 16 tx lanes (lanes with equal ty are contiguous)
            #pragma unroll
            for (int m = 1; m < 16; m <<= 1) {
                float ov = __shfl_xor(bv, m, 64);
                int oj = __shfl_xor(bj, m, 64);
                if (ov > bv || (ov == bv && oj < bj)) { bv = ov; bj = oj; }
            }
            if (bv > best[i] || (bv == best[i] && bj < bi_[i])) { best[i] = bv; bi_[i] = bj; }
        }
    }

    if (tx == 0) {
        #pragma unroll
        for (int i = 0; i < 8; ++i) {
            int r = row0 + ty * 8 + i;
            bval[(size_t)r * NC + chunk] = best[i];
            bidx[(size_t)r * NC + chunk] = bi_[i];
        }
    }
}

// ---------------- cross-chunk argmin reduce ----------------

__global__ void reduce_rows_kernel(const float* __restrict__ bval, const int* __restrict__ bidx,
                                   int* __restrict__ rows_idx, float* __restrict__ out_idx) {
    int row = blockIdx.x * blockDim.x + threadIdx.x;
    if (row >= ZM) return;
    float bv = -FLT_MAX; int bi = 0;
    #pragma unroll
    for (int c = 0; c < NC; ++c) {
        float v = bval[(size_t)row * NC + c];
        int i = bidx[(size_t)row * NC + c];
        if (v > bv || (v == bv && i < bi)) { bv = v; bi = i; }
    }
    rows_idx[row] = bi;
    out_idx[row] = (float)bi;   // harness reads d_out as float32
}

// ---------------- gather + loss partials ----------------

__global__ void finalize_kernel(const float* __restrict__ z, const float* __restrict__ cb,
                                const int* __restrict__ rows_idx,
                                float* __restrict__ zq_out, float* __restrict__ lpart) {
    __shared__ float sm[4];
    int row = blockIdx.x;
    int b = row >> 10, hw = row & (HWN - 1);
    int c = threadIdx.x;
    int idx = rows_idx[row];
    float zq = cb[(size_t)idx * KD + c];                    // RAW codebook gather
    size_t zo = (size_t)b * ZSTRIDE + (size_t)c * HWN + hw;
    float zt = z[zo];
    float d = zq - zt;
    zq_out[zo] = zt + d;                                    // straight-through arithmetic
    float s = d * d;
    #pragma unroll
    for (int m = 32; m; m >>= 1) s += __shfl_xor(s, m, 64);
    if ((threadIdx.x & 63) == 0) sm[threadIdx.x >> 6] = s;
    __syncthreads();
    if (threadIdx.x == 0) lpart[row] = sm[0] + sm[1] + sm[2] + sm[3];
}

__global__ void loss_final_kernel(const float* __restrict__ lpart, float* __restrict__ out) {
    __shared__ float sm[4];
    float s = 0.0f;
    for (int i = threadIdx.x; i < ZM; i += 256) s += lpart[i];
    #pragma unroll
    for (int m = 32; m; m >>= 1) s += __shfl_xor(s, m, 64);
    if ((threadIdx.x & 63) == 0) sm[threadIdx.x >> 6] = s;
    __syncthreads();
    if (threadIdx.x == 0) {
        float total = sm[0] + sm[1] + sm[2] + sm[3];
        float m = total * (1.0f / 2097152.0f);
        out[0] = fmaf(0.25f, m, m);   // BETA*mean + mean
    }
}

// ---------------- launch ----------------

extern "C" void kernel_launch(void* const* d_in, const int* in_sizes, int n_in,
                              void* d_out, int out_size, void* d_ws, size_t ws_size,
                              hipStream_t stream) {
    const float* z  = (const float*)d_in[0];
    const float* cb = (const float*)d_in[1];
    float* out = (float*)d_out;

    // ws layout (floats)
    float* ws = (float*)d_ws;
    float* zrinv  = ws;                         // 8192
    float* cbrinv = zrinv + ZM;                 // 16384
    float* cbsq   = cbrinv + CN;                // 16384
    float* bval   = cbsq + CN;                  // ZM*NC
    int*   bidx   = (int*)(bval + (size_t)ZM * NC); // ZM*NC
    float* lpart  = (float*)(bidx + (size_t)ZM * NC); // 8192
    int*   ridx   = (int*)(lpart + ZM);         // 8192

    float* out_loss = out;
    float* out_zq   = out + 1;
    float* out_idx  = out + 1 + (size_t)ZM * KD;

    norm_z_kernel<<<ZM, 256, 0, stream>>>(z, zrinv);
    norm_cb_kernel<<<CN, 256, 0, stream>>>(cb, cbrinv, cbsq);
    gemm_argmin_kernel<<<dim3(ZM / BM, NC), 256, 0, stream>>>(z, cb, zrinv, cbrinv, cbsq, bval, bidx);
    reduce_rows_kernel<<<ZM / 256, 256, 0, stream>>>(bval, bidx, ridx, out_idx);
    finalize_kernel<<<ZM, 256, 0, stream>>>(z, cb, ridx, out_zq, lpart);
    loss_final_kernel<<<1, 256, 0, stream>>>(lpart, out_loss);
}